// Round 2
// baseline (80.826 us; speedup 1.0000x reference)
//
#include <hip/hip_runtime.h>
#include <stdint.h>

// HypervectorEngine: signal (512,8192) f32 -> sparse (512,4096) f32 in {-1,0,+1}
// Bit-exact replica of JAX reference (threefry partitionable path; absmax=0
// verified). seed = pos ^ rne(v*1000) < 1024 -> only 1024 distinct
// hypervectors: build a BIT-PACKED table (1024 x 512 B, L2-resident),
// then per-row gather-sum + exact stable top-k(2048) by |sum| with sign emit.
//
// R5: (a) __mul24 (v_mul_u32_u24, full-rate) for the 40 nibble-spread
// multiplies (was quarter-rate v_mul_lo_u32); (b) group-reduce uses all 512
// threads (2 items each) instead of t<128 x 8; (c) 8-way per-wave histogram
// privatization (was 4) -> atomic contention intra-wave only; (d) fully
// unrolled 25-load gather so all L2 loads issue ahead of the CSA chain.

#define B_ROWS 512
#define SIG_L  8192
#define DIM    4096
#define NS     100
#define NKEY   2048
#define NSEED  1024

__device__ __forceinline__ void tf2x32(uint32_t k0, uint32_t k1,
                                       uint32_t& x0, uint32_t& x1) {
  const uint32_t k2 = k0 ^ k1 ^ 0x1BD11BDAu;
  x0 += k0; x1 += k1;
#define TF_RND(r) { x0 += x1; x1 = (x1 << (r)) | (x1 >> (32 - (r))); x1 ^= x0; }
  TF_RND(13) TF_RND(15) TF_RND(26) TF_RND(6)
  x0 += k1; x1 += k2 + 1u;
  TF_RND(17) TF_RND(29) TF_RND(16) TF_RND(24)
  x0 += k2; x1 += k0 + 2u;
  TF_RND(13) TF_RND(15) TF_RND(26) TF_RND(6)
  x0 += k0; x1 += k1 + 3u;
  TF_RND(17) TF_RND(29) TF_RND(16) TF_RND(24)
  x0 += k1; x1 += k2 + 4u;
  TF_RND(13) TF_RND(15) TF_RND(26) TF_RND(6)
  x0 += k2; x1 += k0 + 5u;
#undef TF_RND
}

// 32 random bits for element i under folded key (partitionable path).
__device__ __forceinline__ uint32_t rbits32(uint32_t k0, uint32_t k1, uint32_t i) {
  uint32_t x0 = 0u, x1 = i;
  tf2x32(k0, k1, x0, x1);
  return x0 ^ x1;
}

// Nibble (<=15) -> 4 bytes of 0/1. Operands < 2^23: v_mul_u32_u24 exact,
// full-rate (v_mul_lo_u32 is quarter-rate).
__device__ __forceinline__ uint32_t spread4(uint32_t nib) {
  return ((uint32_t)__mul24((int)nib, 0x00204081) & 0x01010101u);
}

// ---- Kernel A: bit-packed table. bit=1 <=> element is -1 (top bit of rbits).
// Layout: table[seed] is 512 B; little-endian, bit p of dword j = dim 32j+p.
__global__ __launch_bounds__(256) void build_table_kernel(uint16_t* __restrict__ tbl16) {
  const int seed = blockIdx.x;
  __shared__ uint32_t kk[2];
  if (threadIdx.x == 0) {
    uint32_t x0 = 0u, x1 = (uint32_t)seed;   // fold_in: cipher((0,42),(0,seed))
    tf2x32(0u, 42u, x0, x1);
    kk[0] = x0; kk[1] = x1;
  }
  __syncthreads();
  const uint32_t k0 = kk[0], k1 = kk[1];
  const int base = threadIdx.x * 16;         // 16 consecutive dims per thread
  uint32_t bits16 = 0;
#pragma unroll
  for (int k = 0; k < 16; ++k) {
    uint32_t b = rbits32(k0, k1, (uint32_t)(base + k)) >> 31;
    bits16 |= b << k;
  }
  tbl16[seed * 256 + threadIdx.x] = (uint16_t)bits16;   // 128 B/wave coalesced
}

// ---- Kernel B (table path): one block (512 thr) per row.
// Thread t: dim-group j=t&127 (dims 32j..32j+31), sample-residue g=t>>7
// (samples s = g, g+4, ..., 25 each). CSA bit-plane counts, LDS-reduced.
__global__ __launch_bounds__(512) void row_kernel_t(const float* __restrict__ signal,
                                                    const uint32_t* __restrict__ tbl32,
                                                    float* __restrict__ out) {
  const int b = blockIdx.x;
  const int t = threadIdx.x;
  const int j = t & 127;
  const int g = t >> 7;
  __shared__ uint32_t sseed[NS];
  __shared__ int      hist8[8 * 51];  // |combined| even: bin=a>>1; copy per wave
  __shared__ int      wsum[8];
  __shared__ int      TQ[2];
  __shared__ uint32_t red[512 * 9];   // stride 9 -> conflict-free

  if (t < 8 * 51) hist8[t] = 0;
  if (t < NS) {
    const float step = 8191.0f / 99.0f;            // linspace(0, L-1, 100) step
    float idxf = (float)t * step;
    int   idx  = (int)idxf;                         // astype(int32): trunc
    float v    = signal[b * SIG_L + idx];
    int   val  = __float2int_rn(v * 1000.0f);       // jnp.round: half-to-even
    sseed[t] = (uint32_t)(t ^ val);                 // pos ^ val_seed (< 1024)
  }
  __syncthreads();

  // 25 dword gathers; carry-save adder over 5 bit planes (max count 25 < 32).
  // Fully unrolled: all 25 independent L2 loads can issue ahead of the chain.
  uint32_t p0 = 0, p1 = 0, p2 = 0, p3 = 0, p4 = 0;
#pragma unroll
  for (int s = g; s < NS; s += 4) {
    const uint32_t m = tbl32[(sseed[s] << 7) + j];
    uint32_t c0 = p0 & m;  p0 ^= m;
    uint32_t c1 = p1 & c0; p1 ^= c0;
    uint32_t c2 = p2 & c1; p2 ^= c1;
    uint32_t c3 = p3 & c2; p3 ^= c2;
    p4 ^= c3;                                      // weight-16 plane, no carry out
  }

  // Extract byte-packed minus-counts: byte i of word q = count of dim 32j+4q+i.
#pragma unroll
  for (int q = 0; q < 8; ++q) {
    uint32_t e  =  spread4((p0 >> (4 * q)) & 0xFu);
    e += spread4((p1 >> (4 * q)) & 0xFu) << 1;
    e += spread4((p2 >> (4 * q)) & 0xFu) << 2;
    e += spread4((p3 >> (4 * q)) & 0xFu) << 3;
    e += spread4((p4 >> (4 * q)) & 0xFu) << 4;
    red[t * 9 + q] = e;                            // bytes <= 25
  }
  __syncthreads();

  // Reduce the 4 sample-groups (bytes <=25 each, sum <=100: no carry).
  // All 512 threads: 2 of the 1024 (j,q) items each. Each item is read+written
  // by exactly one thread; reads from j+128/256/384 are never written here.
#pragma unroll
  for (int i = t; i < 1024; i += 512) {
    const int jj = i >> 3, q = i & 7;
    uint32_t s0 = red[(jj      ) * 9 + q] + red[(jj + 128) * 9 + q];
    uint32_t s1 = red[(jj + 256) * 9 + q] + red[(jj + 384) * 9 + q];
    red[jj * 9 + q] = s0 + s1;
  }
  __syncthreads();

  // Back to 8 dims/thread: dims 8t..8t+7 = global words 2t, 2t+1.
  const uint32_t cw0 = red[(t >> 2) * 9 + 2 * (t & 3)];
  const uint32_t cw1 = red[(t >> 2) * 9 + 2 * (t & 3) + 1];
  int acc[8];
#pragma unroll
  for (int k = 0; k < 4; ++k) {
    acc[k]     = NS - 2 * (int)((cw0 >> (8 * k)) & 0xFFu);
    acc[k + 4] = NS - 2 * (int)((cw1 >> (8 * k)) & 0xFFu);
  }

  const int lane = t & 63, wv = t >> 6;

  // Histogram of |combined|>>1 (values even, in [0,100]); copy per wave.
#pragma unroll
  for (int k = 0; k < 8; ++k) {
    int a = acc[k] < 0 ? -acc[k] : acc[k];
    atomicAdd(&hist8[wv * 51 + (a >> 1)], 1);
  }
  __syncthreads();

  // Threshold T + tie quota Q: wave 0 does a 6-step suffix scan over 51 bins.
  if (t < 64) {
    int cnt = 0;
    if (t < 51) {
      cnt = hist8[t]        + hist8[51 + t]  + hist8[102 + t] + hist8[153 + t]
          + hist8[204 + t]  + hist8[255 + t] + hist8[306 + t] + hist8[357 + t];
    }
    int S = cnt;                                   // S[l] = sum_{x>=l} cnt[x]
#pragma unroll
    for (int off = 1; off < 64; off <<= 1) {
      int n = __shfl_down(S, off, 64);
      if (t + off < 64) S += n;
    }
    int Sx = S - cnt;                              // strictly-greater count
    if (Sx < NKEY && S >= NKEY) { TQ[0] = 2 * t; TQ[1] = NKEY - Sx; }
  }
  __syncthreads();
  const int T = TQ[0];
  const int Q = TQ[1];

  // Exclusive prefix of tie counts in dim order: wave shfl-scan + wave offsets.
  int cnt = 0;
#pragma unroll
  for (int k = 0; k < 8; ++k) {
    int a = acc[k] < 0 ? -acc[k] : acc[k];
    cnt += (a == T);
  }
  int sc = cnt;
#pragma unroll
  for (int off = 1; off < 64; off <<= 1) {
    int n = __shfl_up(sc, off, 64);
    if (lane >= off) sc += n;
  }
  if (lane == 63) wsum[wv] = sc;
  __syncthreads();
  int prefix = sc - cnt;                 // exclusive within wave
  for (int w = 0; w < wv; ++w) prefix += wsum[w];

  float o[8];
#pragma unroll
  for (int k = 0; k < 8; ++k) {
    int   v = acc[k];
    int   a = v < 0 ? -v : v;
    float sg = v > 0 ? 1.0f : (v < 0 ? -1.0f : 0.0f);
    float r = 0.0f;
    if (a > T) {
      r = sg;
    } else if (a == T) {
      if (prefix < Q) r = sg;            // stable ties: lower index first
      prefix++;
    }
    o[k] = r;
  }
  float4* op = (float4*)(out + (size_t)b * DIM + t * 8);
  op[0] = make_float4(o[0], o[1], o[2], o[3]);
  op[1] = make_float4(o[4], o[5], o[6], o[7]);
}

// ---- Fallback (ws too small): on-the-fly ciphers, 8 dims/thread ----
__global__ __launch_bounds__(512) void row_kernel_f(const float* __restrict__ signal,
                                                    float* __restrict__ out) {
  const int b = blockIdx.x;
  const int t = threadIdx.x;
  __shared__ uint32_t sk0[NS], sk1[NS];
  __shared__ int      hist[101];
  __shared__ int      wsum[8];
  __shared__ int      TQ[2];

  if (t < 101) hist[t] = 0;
  if (t < NS) {
    const float step = 8191.0f / 99.0f;
    int   idx  = (int)((float)t * step);
    float v    = signal[b * SIG_L + idx];
    int   val  = __float2int_rn(v * 1000.0f);
    int   sd   = t ^ val;
    uint32_t x0 = 0u, x1 = (uint32_t)sd;
    tf2x32(0u, 42u, x0, x1);
    sk0[t] = x0; sk1[t] = x1;
  }
  __syncthreads();

  uint32_t c_lo = 0, c_hi = 0;
  for (int s = 0; s < NS; ++s) {
    uint32_t m = 0;
    const uint32_t k0 = sk0[s], k1 = sk1[s];
    for (int jj = 0; jj < 8; ++jj)
      m |= (rbits32(k0, k1, (uint32_t)(8 * t + jj)) >> 31) << jj;
    c_lo += spread4(m & 0xFu);
    c_hi += spread4(m >> 4);
  }
  int acc[8];
#pragma unroll
  for (int k = 0; k < 4; ++k) {
    acc[k]     = NS - 2 * (int)((c_lo >> (8 * k)) & 0xFFu);
    acc[k + 4] = NS - 2 * (int)((c_hi >> (8 * k)) & 0xFFu);
  }
#pragma unroll
  for (int k = 0; k < 8; ++k) {
    int a = acc[k] < 0 ? -acc[k] : acc[k];
    atomicAdd(&hist[a], 1);
  }
  __syncthreads();
  if (t < 101) {
    int cum = 0;
    for (int x = t + 1; x <= 100; ++x) cum += hist[x];
    if (cum < NKEY && cum + hist[t] >= NKEY) { TQ[0] = t; TQ[1] = NKEY - cum; }
  }
  __syncthreads();
  const int T = TQ[0];
  const int Q = TQ[1];
  int cnt = 0;
#pragma unroll
  for (int k = 0; k < 8; ++k) {
    int a = acc[k] < 0 ? -acc[k] : acc[k];
    cnt += (a == T);
  }
  const int lane = t & 63, wv = t >> 6;
  int sc = cnt;
#pragma unroll
  for (int off = 1; off < 64; off <<= 1) {
    int n = __shfl_up(sc, off, 64);
    if (lane >= off) sc += n;
  }
  if (lane == 63) wsum[wv] = sc;
  __syncthreads();
  int prefix = sc - cnt;
  for (int w = 0; w < wv; ++w) prefix += wsum[w];
  float o[8];
#pragma unroll
  for (int k = 0; k < 8; ++k) {
    int   v = acc[k];
    int   a = v < 0 ? -v : v;
    float sg = v > 0 ? 1.0f : (v < 0 ? -1.0f : 0.0f);
    float r = 0.0f;
    if (a > T) r = sg;
    else if (a == T) { if (prefix < Q) r = sg; prefix++; }
    o[k] = r;
  }
  float4* op = (float4*)(out + (size_t)b * DIM + t * 8);
  op[0] = make_float4(o[0], o[1], o[2], o[3]);
  op[1] = make_float4(o[4], o[5], o[6], o[7]);
}

extern "C" void kernel_launch(void* const* d_in, const int* in_sizes, int n_in,
                              void* d_out, int out_size, void* d_ws, size_t ws_size,
                              hipStream_t stream) {
  (void)in_sizes; (void)n_in; (void)out_size;
  const float* signal = (const float*)d_in[0];
  float* out = (float*)d_out;
  const size_t table_bytes = (size_t)NSEED * (DIM / 8);   // 512 KB bit-packed

  if (ws_size >= table_bytes) {
    build_table_kernel<<<NSEED, 256, 0, stream>>>((uint16_t*)d_ws);
    row_kernel_t<<<B_ROWS, 512, 0, stream>>>(signal, (const uint32_t*)d_ws, out);
  } else {
    row_kernel_f<<<B_ROWS, 512, 0, stream>>>(signal, out);
  }
}

// Round 3
// 77.740 us; speedup vs baseline: 1.0397x; 1.0397x over previous
//
#include <hip/hip_runtime.h>
#include <stdint.h>

// HypervectorEngine: signal (512,8192) f32 -> sparse (512,4096) f32 in {-1,0,+1}
// Bit-exact replica of JAX reference (threefry partitionable path; absmax=0
// verified). seed = pos ^ rne(v*1000) < 1024 -> only 1024 distinct
// hypervectors: build a BIT-PACKED table (1024 x 512 B, L2-resident),
// then per-row gather-sum + exact stable top-k(2048) by |sum| with sign emit.
//
// R6: de-bundle R5. Keep R1's gather structure (#pragma unroll 5 -- the R5
// full unroll coincided with a +2.8us regression) and keep only the
// instruction-level-safe R5 changes: (a) __mul24 full-rate nibble spread,
// (b) full-width 512-thread group reduce, (c) 8-way per-wave histogram.

#define B_ROWS 512
#define SIG_L  8192
#define DIM    4096
#define NS     100
#define NKEY   2048
#define NSEED  1024

__device__ __forceinline__ void tf2x32(uint32_t k0, uint32_t k1,
                                       uint32_t& x0, uint32_t& x1) {
  const uint32_t k2 = k0 ^ k1 ^ 0x1BD11BDAu;
  x0 += k0; x1 += k1;
#define TF_RND(r) { x0 += x1; x1 = (x1 << (r)) | (x1 >> (32 - (r))); x1 ^= x0; }
  TF_RND(13) TF_RND(15) TF_RND(26) TF_RND(6)
  x0 += k1; x1 += k2 + 1u;
  TF_RND(17) TF_RND(29) TF_RND(16) TF_RND(24)
  x0 += k2; x1 += k0 + 2u;
  TF_RND(13) TF_RND(15) TF_RND(26) TF_RND(6)
  x0 += k0; x1 += k1 + 3u;
  TF_RND(17) TF_RND(29) TF_RND(16) TF_RND(24)
  x0 += k1; x1 += k2 + 4u;
  TF_RND(13) TF_RND(15) TF_RND(26) TF_RND(6)
  x0 += k2; x1 += k0 + 5u;
#undef TF_RND
}

// 32 random bits for element i under folded key (partitionable path).
__device__ __forceinline__ uint32_t rbits32(uint32_t k0, uint32_t k1, uint32_t i) {
  uint32_t x0 = 0u, x1 = i;
  tf2x32(k0, k1, x0, x1);
  return x0 ^ x1;
}

// Nibble (<=15) -> 4 bytes of 0/1. Operands < 2^23: v_mul_u32_u24 exact,
// full-rate (v_mul_lo_u32 is quarter-rate).
__device__ __forceinline__ uint32_t spread4(uint32_t nib) {
  return ((uint32_t)__mul24((int)nib, 0x00204081) & 0x01010101u);
}

// ---- Kernel A: bit-packed table. bit=1 <=> element is -1 (top bit of rbits).
// Layout: table[seed] is 512 B; little-endian, bit p of dword j = dim 32j+p.
__global__ __launch_bounds__(256) void build_table_kernel(uint16_t* __restrict__ tbl16) {
  const int seed = blockIdx.x;
  __shared__ uint32_t kk[2];
  if (threadIdx.x == 0) {
    uint32_t x0 = 0u, x1 = (uint32_t)seed;   // fold_in: cipher((0,42),(0,seed))
    tf2x32(0u, 42u, x0, x1);
    kk[0] = x0; kk[1] = x1;
  }
  __syncthreads();
  const uint32_t k0 = kk[0], k1 = kk[1];
  const int base = threadIdx.x * 16;         // 16 consecutive dims per thread
  uint32_t bits16 = 0;
#pragma unroll
  for (int k = 0; k < 16; ++k) {
    uint32_t b = rbits32(k0, k1, (uint32_t)(base + k)) >> 31;
    bits16 |= b << k;
  }
  tbl16[seed * 256 + threadIdx.x] = (uint16_t)bits16;   // 128 B/wave coalesced
}

// ---- Kernel B (table path): one block (512 thr) per row.
// Thread t: dim-group j=t&127 (dims 32j..32j+31), sample-residue g=t>>7
// (samples s = g, g+4, ..., 25 each). CSA bit-plane counts, LDS-reduced.
__global__ __launch_bounds__(512) void row_kernel_t(const float* __restrict__ signal,
                                                    const uint32_t* __restrict__ tbl32,
                                                    float* __restrict__ out) {
  const int b = blockIdx.x;
  const int t = threadIdx.x;
  const int j = t & 127;
  const int g = t >> 7;
  __shared__ uint32_t sseed[NS];
  __shared__ int      hist8[8 * 51];  // |combined| even: bin=a>>1; copy per wave
  __shared__ int      wsum[8];
  __shared__ int      TQ[2];
  __shared__ uint32_t red[512 * 9];   // stride 9 -> conflict-free

  if (t < 8 * 51) hist8[t] = 0;
  if (t < NS) {
    const float step = 8191.0f / 99.0f;            // linspace(0, L-1, 100) step
    float idxf = (float)t * step;
    int   idx  = (int)idxf;                         // astype(int32): trunc
    float v    = signal[b * SIG_L + idx];
    int   val  = __float2int_rn(v * 1000.0f);       // jnp.round: half-to-even
    sseed[t] = (uint32_t)(t ^ val);                 // pos ^ val_seed (< 1024)
  }
  __syncthreads();

  // 25 dword gathers; carry-save adder over 5 bit planes (max count 25 < 32).
  // NOTE: unroll 5 (not full) -- R5's full unroll coincided with a regression.
  uint32_t p0 = 0, p1 = 0, p2 = 0, p3 = 0, p4 = 0;
#pragma unroll 5
  for (int s = g; s < NS; s += 4) {
    const uint32_t m = tbl32[(sseed[s] << 7) + j];
    uint32_t c0 = p0 & m;  p0 ^= m;
    uint32_t c1 = p1 & c0; p1 ^= c0;
    uint32_t c2 = p2 & c1; p2 ^= c1;
    uint32_t c3 = p3 & c2; p3 ^= c2;
    p4 ^= c3;                                      // weight-16 plane, no carry out
  }

  // Extract byte-packed minus-counts: byte i of word q = count of dim 32j+4q+i.
#pragma unroll
  for (int q = 0; q < 8; ++q) {
    uint32_t e  =  spread4((p0 >> (4 * q)) & 0xFu);
    e += spread4((p1 >> (4 * q)) & 0xFu) << 1;
    e += spread4((p2 >> (4 * q)) & 0xFu) << 2;
    e += spread4((p3 >> (4 * q)) & 0xFu) << 3;
    e += spread4((p4 >> (4 * q)) & 0xFu) << 4;
    red[t * 9 + q] = e;                            // bytes <= 25
  }
  __syncthreads();

  // Reduce the 4 sample-groups (bytes <=25 each, sum <=100: no carry).
  // All 512 threads: 2 of the 1024 (j,q) items each. Each item is read+written
  // by exactly one thread; source rows (jj+128/256/384) are never written here.
#pragma unroll
  for (int i = t; i < 1024; i += 512) {
    const int jj = i >> 3, q = i & 7;
    uint32_t s0 = red[(jj      ) * 9 + q] + red[(jj + 128) * 9 + q];
    uint32_t s1 = red[(jj + 256) * 9 + q] + red[(jj + 384) * 9 + q];
    red[jj * 9 + q] = s0 + s1;
  }
  __syncthreads();

  // Back to 8 dims/thread: dims 8t..8t+7 = global words 2t, 2t+1.
  const uint32_t cw0 = red[(t >> 2) * 9 + 2 * (t & 3)];
  const uint32_t cw1 = red[(t >> 2) * 9 + 2 * (t & 3) + 1];
  int acc[8];
#pragma unroll
  for (int k = 0; k < 4; ++k) {
    acc[k]     = NS - 2 * (int)((cw0 >> (8 * k)) & 0xFFu);
    acc[k + 4] = NS - 2 * (int)((cw1 >> (8 * k)) & 0xFFu);
  }

  const int lane = t & 63, wv = t >> 6;

  // Histogram of |combined|>>1 (values even, in [0,100]); copy per wave.
#pragma unroll
  for (int k = 0; k < 8; ++k) {
    int a = acc[k] < 0 ? -acc[k] : acc[k];
    atomicAdd(&hist8[wv * 51 + (a >> 1)], 1);
  }
  __syncthreads();

  // Threshold T + tie quota Q: wave 0 does a 6-step suffix scan over 51 bins.
  if (t < 64) {
    int cnt = 0;
    if (t < 51) {
      cnt = hist8[t]        + hist8[51 + t]  + hist8[102 + t] + hist8[153 + t]
          + hist8[204 + t]  + hist8[255 + t] + hist8[306 + t] + hist8[357 + t];
    }
    int S = cnt;                                   // S[l] = sum_{x>=l} cnt[x]
#pragma unroll
    for (int off = 1; off < 64; off <<= 1) {
      int n = __shfl_down(S, off, 64);
      if (t + off < 64) S += n;
    }
    int Sx = S - cnt;                              // strictly-greater count
    if (Sx < NKEY && S >= NKEY) { TQ[0] = 2 * t; TQ[1] = NKEY - Sx; }
  }
  __syncthreads();
  const int T = TQ[0];
  const int Q = TQ[1];

  // Exclusive prefix of tie counts in dim order: wave shfl-scan + wave offsets.
  int cnt = 0;
#pragma unroll
  for (int k = 0; k < 8; ++k) {
    int a = acc[k] < 0 ? -acc[k] : acc[k];
    cnt += (a == T);
  }
  int sc = cnt;
#pragma unroll
  for (int off = 1; off < 64; off <<= 1) {
    int n = __shfl_up(sc, off, 64);
    if (lane >= off) sc += n;
  }
  if (lane == 63) wsum[wv] = sc;
  __syncthreads();
  int prefix = sc - cnt;                 // exclusive within wave
  for (int w = 0; w < wv; ++w) prefix += wsum[w];

  float o[8];
#pragma unroll
  for (int k = 0; k < 8; ++k) {
    int   v = acc[k];
    int   a = v < 0 ? -v : v;
    float sg = v > 0 ? 1.0f : (v < 0 ? -1.0f : 0.0f);
    float r = 0.0f;
    if (a > T) {
      r = sg;
    } else if (a == T) {
      if (prefix < Q) r = sg;            // stable ties: lower index first
      prefix++;
    }
    o[k] = r;
  }
  float4* op = (float4*)(out + (size_t)b * DIM + t * 8);
  op[0] = make_float4(o[0], o[1], o[2], o[3]);
  op[1] = make_float4(o[4], o[5], o[6], o[7]);
}

// ---- Fallback (ws too small): on-the-fly ciphers, 8 dims/thread ----
__global__ __launch_bounds__(512) void row_kernel_f(const float* __restrict__ signal,
                                                    float* __restrict__ out) {
  const int b = blockIdx.x;
  const int t = threadIdx.x;
  __shared__ uint32_t sk0[NS], sk1[NS];
  __shared__ int      hist[101];
  __shared__ int      wsum[8];
  __shared__ int      TQ[2];

  if (t < 101) hist[t] = 0;
  if (t < NS) {
    const float step = 8191.0f / 99.0f;
    int   idx  = (int)((float)t * step);
    float v    = signal[b * SIG_L + idx];
    int   val  = __float2int_rn(v * 1000.0f);
    int   sd   = t ^ val;
    uint32_t x0 = 0u, x1 = (uint32_t)sd;
    tf2x32(0u, 42u, x0, x1);
    sk0[t] = x0; sk1[t] = x1;
  }
  __syncthreads();

  uint32_t c_lo = 0, c_hi = 0;
  for (int s = 0; s < NS; ++s) {
    uint32_t m = 0;
    const uint32_t k0 = sk0[s], k1 = sk1[s];
    for (int jj = 0; jj < 8; ++jj)
      m |= (rbits32(k0, k1, (uint32_t)(8 * t + jj)) >> 31) << jj;
    c_lo += spread4(m & 0xFu);
    c_hi += spread4(m >> 4);
  }
  int acc[8];
#pragma unroll
  for (int k = 0; k < 4; ++k) {
    acc[k]     = NS - 2 * (int)((c_lo >> (8 * k)) & 0xFFu);
    acc[k + 4] = NS - 2 * (int)((c_hi >> (8 * k)) & 0xFFu);
  }
#pragma unroll
  for (int k = 0; k < 8; ++k) {
    int a = acc[k] < 0 ? -acc[k] : acc[k];
    atomicAdd(&hist[a], 1);
  }
  __syncthreads();
  if (t < 101) {
    int cum = 0;
    for (int x = t + 1; x <= 100; ++x) cum += hist[x];
    if (cum < NKEY && cum + hist[t] >= NKEY) { TQ[0] = t; TQ[1] = NKEY - cum; }
  }
  __syncthreads();
  const int T = TQ[0];
  const int Q = TQ[1];
  int cnt = 0;
#pragma unroll
  for (int k = 0; k < 8; ++k) {
    int a = acc[k] < 0 ? -acc[k] : acc[k];
    cnt += (a == T);
  }
  const int lane = t & 63, wv = t >> 6;
  int sc = cnt;
#pragma unroll
  for (int off = 1; off < 64; off <<= 1) {
    int n = __shfl_up(sc, off, 64);
    if (lane >= off) sc += n;
  }
  if (lane == 63) wsum[wv] = sc;
  __syncthreads();
  int prefix = sc - cnt;
  for (int w = 0; w < wv; ++w) prefix += wsum[w];
  float o[8];
#pragma unroll
  for (int k = 0; k < 8; ++k) {
    int   v = acc[k];
    int   a = v < 0 ? -v : v;
    float sg = v > 0 ? 1.0f : (v < 0 ? -1.0f : 0.0f);
    float r = 0.0f;
    if (a > T) r = sg;
    else if (a == T) { if (prefix < Q) r = sg; prefix++; }
    o[k] = r;
  }
  float4* op = (float4*)(out + (size_t)b * DIM + t * 8);
  op[0] = make_float4(o[0], o[1], o[2], o[3]);
  op[1] = make_float4(o[4], o[5], o[6], o[7]);
}

extern "C" void kernel_launch(void* const* d_in, const int* in_sizes, int n_in,
                              void* d_out, int out_size, void* d_ws, size_t ws_size,
                              hipStream_t stream) {
  (void)in_sizes; (void)n_in; (void)out_size;
  const float* signal = (const float*)d_in[0];
  float* out = (float*)d_out;
  const size_t table_bytes = (size_t)NSEED * (DIM / 8);   // 512 KB bit-packed

  if (ws_size >= table_bytes) {
    build_table_kernel<<<NSEED, 256, 0, stream>>>((uint16_t*)d_ws);
    row_kernel_t<<<B_ROWS, 512, 0, stream>>>(signal, (const uint32_t*)d_ws, out);
  } else {
    row_kernel_f<<<B_ROWS, 512, 0, stream>>>(signal, out);
  }
}